// Round 2
// 269.524 us; speedup vs baseline: 1.0152x; 1.0152x over previous
//
#include <hip/hip_runtime.h>
#include <math.h>

// Problem constants
#define T_DIM 1024
#define N_DIM 8192
#define M_TOT (T_DIM * N_DIM)          // 8,388,608
#define NV4   (N_DIM / 4)              // 2048 vec4 per row
#define L_CHUNK 8
#define C_CHUNKS (T_DIM / L_CHUNK)     // 128
#define PC_BLOCKS ((C_CHUNKS * NV4) / 256)   // 1024
#define SCAN_BLOCKS ((NV4 * 16) / 256)       // 128

#define kGAMMA 0.99f
#define kGLAM  (0.99f * 0.95f)

// ws layout (~24.06 MB):
//   +256          pg [1024][3] doubles (24 KB)  -- k_gae block partials
//   +32768        pl [1024][2] doubles (16 KB)  -- k_loss block partials
//   +65536        b16 [T][N] ushort (16 MB)     -- persists through k_loss
//   +65536+16MB   A   [C][N] float (4 MB)       -- chunk-map A, overwritten w/ g_in
//   +65536+20MB   B   [C][N] float (4 MB)

__device__ __forceinline__ unsigned short f2bf(float f) {
    unsigned int u = __float_as_uint(f);
    u += 0x7fffu + ((u >> 16) & 1u);        // round-to-nearest-even
    return (unsigned short)(u >> 16);
}
__device__ __forceinline__ float bf2f(unsigned short h) {
    return __uint_as_float(((unsigned int)h) << 16);
}

// ---------------------------------------------------------------------------
// K1: fused prep+chunk (PROVEN). Thread (c, j): row-serial descending-t loop
// with vnext carry; computes b_t (bf16, a-bit in LSB) AND the chunk map (A,B).
__global__ __launch_bounds__(256) void k_pc(
    const float4* __restrict__ r4,
    const float4* __restrict__ m4,     // (T+1) rows
    const float4* __restrict__ bm4,    // (T+1) rows
    const float4* __restrict__ vp4,    // (T+1) rows
    const float4* __restrict__ lv4,    // (N,)
    ushort4* __restrict__ b16,
    float4* __restrict__ A_out,
    float4* __restrict__ B_out)
{
    const int g  = blockIdx.x * 256 + threadIdx.x;   // 0 .. C*NV4-1
    const int j  = g & (NV4 - 1);
    const int c  = g >> 11;
    const int t0 = c * L_CHUNK;

    float4 vnext = (c == C_CHUNKS - 1) ? lv4[j] : vp4[(t0 + L_CHUNK) * NV4 + j];
    float4 Aa = make_float4(1.f, 1.f, 1.f, 1.f);
    float4 Bb = make_float4(0.f, 0.f, 0.f, 0.f);

    #pragma unroll
    for (int i = L_CHUNK - 1; i >= 0; --i) {
        const int idx = (t0 + i) * NV4 + j;
        const float4 r  = r4[idx];
        const float4 v  = vp4[idx];
        const float4 m  = m4[idx + NV4];             // row t+1
        const float4 bb = bm4[idx + NV4];            // row t+1

        ushort4 o;
        {
            const float b = (fmaf(kGAMMA * m.x, vnext.x, r.x) - v.x) * bb.x;
            const float a = kGLAM * m.x * bb.x;
            Aa.x = a * Aa.x; Bb.x = fmaf(a, Bb.x, b);
            o.x = (unsigned short)((f2bf(b) & 0xFFFEu) | ((m.x * bb.x > 0.5f) ? 1u : 0u));
        }
        {
            const float b = (fmaf(kGAMMA * m.y, vnext.y, r.y) - v.y) * bb.y;
            const float a = kGLAM * m.y * bb.y;
            Aa.y = a * Aa.y; Bb.y = fmaf(a, Bb.y, b);
            o.y = (unsigned short)((f2bf(b) & 0xFFFEu) | ((m.y * bb.y > 0.5f) ? 1u : 0u));
        }
        {
            const float b = (fmaf(kGAMMA * m.z, vnext.z, r.z) - v.z) * bb.z;
            const float a = kGLAM * m.z * bb.z;
            Aa.z = a * Aa.z; Bb.z = fmaf(a, Bb.z, b);
            o.z = (unsigned short)((f2bf(b) & 0xFFFEu) | ((m.z * bb.z > 0.5f) ? 1u : 0u));
        }
        {
            const float b = (fmaf(kGAMMA * m.w, vnext.w, r.w) - v.w) * bb.w;
            const float a = kGLAM * m.w * bb.w;
            Aa.w = a * Aa.w; Bb.w = fmaf(a, Bb.w, b);
            o.w = (unsigned short)((f2bf(b) & 0xFFFEu) | ((m.w * bb.w > 0.5f) ? 1u : 0u));
        }
        b16[idx] = o;
        vnext = v;
    }
    A_out[c * NV4 + j] = Aa;
    B_out[c * NV4 + j] = Bb;
}

// ---------------------------------------------------------------------------
// K2: parallel suffix scan of the 128 affine chunk maps (replaces serial
// k_ginc). Thread (jj, k): slice k = chunks 8k..8k+7 of vec4-env jj.
// 16-lane shuffle groups share one jj. g_in is written over Ag (each slot
// is read then written by exactly one thread -> no cross-thread hazard).
__global__ __launch_bounds__(256) void k_scan(
    float4* __restrict__ Ag,           // in: A, out: g_in
    const float4* __restrict__ Bg)
{
    const int u  = blockIdx.x * 256 + threadIdx.x;   // 0 .. NV4*16-1
    const int jj = u >> 4;
    const int k  = u & 15;

    float4 As[8], Bs[8];
    #pragma unroll
    for (int i = 0; i < 8; ++i) {
        As[i] = Ag[(8 * k + i) * NV4 + jj];
        Bs[i] = Bg[(8 * k + i) * NV4 + jj];
    }
    // slice map M_k = f_{8k} o ... o f_{8k+7} (highest chunk applied first)
    float4 Pa = As[7], Pb = Bs[7];
    #pragma unroll
    for (int i = 6; i >= 0; --i) {
        Pb.x = fmaf(As[i].x, Pb.x, Bs[i].x); Pa.x = As[i].x * Pa.x;
        Pb.y = fmaf(As[i].y, Pb.y, Bs[i].y); Pa.y = As[i].y * Pa.y;
        Pb.z = fmaf(As[i].z, Pb.z, Bs[i].z); Pa.z = As[i].z * Pa.z;
        Pb.w = fmaf(As[i].w, Pb.w, Bs[i].w); Pa.w = As[i].w * Pa.w;
    }
    // inclusive suffix scan across 16 slices: P_k = M_k o M_{k+1} o ... o M_15
    #pragma unroll
    for (int d = 1; d < 16; d <<= 1) {
        const float nax = __shfl_down(Pa.x, d, 16), nay = __shfl_down(Pa.y, d, 16);
        const float naz = __shfl_down(Pa.z, d, 16), naw = __shfl_down(Pa.w, d, 16);
        const float nbx = __shfl_down(Pb.x, d, 16), nby = __shfl_down(Pb.y, d, 16);
        const float nbz = __shfl_down(Pb.z, d, 16), nbw = __shfl_down(Pb.w, d, 16);
        if (k + d < 16) {               // compose: current o neighbor
            Pb.x = fmaf(Pa.x, nbx, Pb.x); Pa.x *= nax;
            Pb.y = fmaf(Pa.y, nby, Pb.y); Pa.y *= nay;
            Pb.z = fmaf(Pa.z, nbz, Pb.z); Pa.z *= naz;
            Pb.w = fmaf(Pa.w, nbw, Pb.w); Pa.w *= naw;
        }
    }
    // incoming gae for slice k = P_{k+1}(0) = B of lane k+1 (0 for k==15)
    float4 G;
    G.x = __shfl_down(Pb.x, 1, 16);
    G.y = __shfl_down(Pb.y, 1, 16);
    G.z = __shfl_down(Pb.z, 1, 16);
    G.w = __shfl_down(Pb.w, 1, 16);
    if (k == 15) G = make_float4(0.f, 0.f, 0.f, 0.f);
    // back-fill per-chunk incoming gae
    #pragma unroll
    for (int i = 7; i >= 0; --i) {
        Ag[(8 * k + i) * NV4 + jj] = G;
        G.x = fmaf(As[i].x, G.x, Bs[i].x);
        G.y = fmaf(As[i].y, G.y, Bs[i].y);
        G.z = fmaf(As[i].z, G.z, Bs[i].z);
        G.w = fmaf(As[i].w, G.w, Bs[i].w);
    }
}

// ---------------------------------------------------------------------------
// K3: recompute gae per element from b16 + g_in (row-serial); fuse value loss
// and sum/sum2 of gae. Block partials -> pg. NO gae16 store (b16 persists).
__device__ __forceinline__ void gae_comp(float& gae, unsigned short h,
                                         float v, float nvv,
                                         float& sg, float& sg2, float& v_s) {
    const float bf = bf2f(h);
    const float a  = (h & 1u) ? kGLAM : 0.0f;
    gae = fmaf(a, gae, bf);
    sg += gae;
    sg2 = fmaf(gae, gae, sg2);
    const float q  = nvv - v;
    const float e1 = q - gae;
    const float e2 = fminf(fmaxf(q, -0.2f), 0.2f) - gae;
    v_s += fmaxf(e1 * e1, e2 * e2);
}

__global__ __launch_bounds__(256) void k_gae(
    const ushort4* __restrict__ b16,
    const float4* __restrict__ g_in4,
    const float4* __restrict__ vp4,
    const float4* __restrict__ nv4,
    double* __restrict__ pg)           // [PC_BLOCKS][3]
{
    const int g  = blockIdx.x * 256 + threadIdx.x;   // 0 .. C*NV4-1
    const int j  = g & (NV4 - 1);
    const int c  = g >> 11;
    const int t0 = c * L_CHUNK;

    float4 gae = g_in4[c * NV4 + j];
    float sg = 0.f, sg2 = 0.f, v_s = 0.f;

    #pragma unroll
    for (int i = L_CHUNK - 1; i >= 0; --i) {
        const int idx = (t0 + i) * NV4 + j;
        const ushort4 h = b16[idx];
        const float4  v = vp4[idx];
        const float4  q = nv4[idx];
        gae_comp(gae.x, h.x, v.x, q.x, sg, sg2, v_s);
        gae_comp(gae.y, h.y, v.y, q.y, sg, sg2, v_s);
        gae_comp(gae.z, h.z, v.z, q.z, sg, sg2, v_s);
        gae_comp(gae.w, h.w, v.w, q.w, sg, sg2, v_s);
    }

    double d0 = (double)sg, d1 = (double)sg2, d2 = (double)v_s;
    #pragma unroll
    for (int off = 32; off > 0; off >>= 1) {
        d0 += __shfl_down(d0, off, 64);
        d1 += __shfl_down(d1, off, 64);
        d2 += __shfl_down(d2, off, 64);
    }
    __shared__ double sh[3][4];
    const int wid = threadIdx.x >> 6, lane = threadIdx.x & 63;
    if (lane == 0) { sh[0][wid] = d0; sh[1][wid] = d1; sh[2][wid] = d2; }
    __syncthreads();
    if (threadIdx.x == 0) {
        double t0s = 0, t1s = 0, t2s = 0;
        #pragma unroll
        for (int w = 0; w < 4; ++w) { t0s += sh[0][w]; t1s += sh[1][w]; t2s += sh[2][w]; }
        pg[blockIdx.x * 3 + 0] = t0s;
        pg[blockIdx.x * 3 + 1] = t1s;
        pg[blockIdx.x * 3 + 2] = t2s;
    }
}

// ---------------------------------------------------------------------------
// K4: action loss + entropy. Absorbs k_stats: every block redundantly
// reduces the 24 KB pg partials (L2-resident) to mu/invs, then recomputes
// gae in fp32 from b16 + g_in (same recurrence as K3). Partials -> pl.
__global__ __launch_bounds__(256) void k_loss(
    const ushort4* __restrict__ b16,
    const float4* __restrict__ g_in4,
    const float4* __restrict__ lp4,
    const float4* __restrict__ plp4,
    const float4* __restrict__ ent4,
    const double* __restrict__ pg,
    double* __restrict__ pl)           // [PC_BLOCKS][2]
{
    __shared__ double sh[3][4];
    __shared__ double bc[2];
    const int tid = threadIdx.x;

    // --- redundant stats reduce (mu, invs) ---
    {
        double s0 = 0.0, s1 = 0.0;
        for (int i = tid; i < PC_BLOCKS; i += 256) {
            s0 += pg[i * 3 + 0];
            s1 += pg[i * 3 + 1];
        }
        #pragma unroll
        for (int off = 32; off > 0; off >>= 1) {
            s0 += __shfl_down(s0, off, 64);
            s1 += __shfl_down(s1, off, 64);
        }
        const int wid = tid >> 6, lane = tid & 63;
        if (lane == 0) { sh[0][wid] = s0; sh[1][wid] = s1; }
        __syncthreads();
        if (tid == 0) {
            double sum = 0, sum2 = 0;
            #pragma unroll
            for (int w = 0; w < 4; ++w) { sum += sh[0][w]; sum2 += sh[1][w]; }
            const double M = (double)M_TOT;
            const double mu = sum / M;
            double var = (sum2 - sum * sum / M) / (M - 1.0);
            if (var < 0.0) var = 0.0;
            bc[0] = mu;
            bc[1] = 1.0 / (sqrt(var) + 1e-5);
        }
        __syncthreads();
    }
    const float mu   = (float)bc[0];
    const float invs = (float)bc[1];

    // --- loss over this block's chunk (same geometry as K3) ---
    const int g  = blockIdx.x * 256 + tid;
    const int j  = g & (NV4 - 1);
    const int c  = g >> 11;
    const int t0 = c * L_CHUNK;

    float4 gv = g_in4[c * NV4 + j];
    float a_s = 0.f, e_s = 0.f;

    #pragma unroll
    for (int i = L_CHUNK - 1; i >= 0; --i) {
        const int idx = (t0 + i) * NV4 + j;
        const ushort4 h = b16[idx];
        const float4 Lp = lp4[idx];
        const float4 Pp = plp4[idx];
        const float4 E  = ent4[idx];
#define P5C(comp, H) { \
        const unsigned short hh = (H); \
        const float bf = bf2f(hh); \
        const float a  = (hh & 1u) ? kGLAM : 0.0f; \
        gv.comp = fmaf(a, gv.comp, bf); \
        const float x  = (gv.comp - mu) * invs; \
        const float rr = __expf(Lp.comp - Pp.comp); \
        const float rc = fminf(fmaxf(rr, 0.8f), 1.2f); \
        a_s += fminf(rr * x, rc * x); }
        P5C(x, h.x) P5C(y, h.y) P5C(z, h.z) P5C(w, h.w)
#undef P5C
        e_s += E.x + E.y + E.z + E.w;
    }

    double d0 = (double)a_s, d1 = (double)e_s;
    #pragma unroll
    for (int off = 32; off > 0; off >>= 1) {
        d0 += __shfl_down(d0, off, 64);
        d1 += __shfl_down(d1, off, 64);
    }
    const int wid = tid >> 6, lane = tid & 63;
    if (lane == 0) { sh[0][wid] = d0; sh[1][wid] = d1; }
    __syncthreads();
    if (tid == 0) {
        double t0s = 0, t1s = 0;
        #pragma unroll
        for (int w = 0; w < 4; ++w) { t0s += sh[0][w]; t1s += sh[1][w]; }
        pl[blockIdx.x * 2 + 0] = t0s;
        pl[blockIdx.x * 2 + 1] = t1s;
    }
}

// ---------------------------------------------------------------------------
// K5: reduce k_gae vsum partials + k_loss partials -> final scalar.
__global__ __launch_bounds__(256) void k_final(
    const double* __restrict__ pg, const double* __restrict__ pl,
    float* __restrict__ out)
{
    double s0 = 0.0, s1 = 0.0, s2 = 0.0;
    for (int i = threadIdx.x; i < PC_BLOCKS; i += 256) {
        s0 += pl[i * 2 + 0];
        s1 += pl[i * 2 + 1];
        s2 += pg[i * 3 + 2];
    }
    #pragma unroll
    for (int off = 32; off > 0; off >>= 1) {
        s0 += __shfl_down(s0, off, 64);
        s1 += __shfl_down(s1, off, 64);
        s2 += __shfl_down(s2, off, 64);
    }
    __shared__ double sh[3][4];
    const int wid = threadIdx.x >> 6, lane = threadIdx.x & 63;
    if (lane == 0) { sh[0][wid] = s0; sh[1][wid] = s1; sh[2][wid] = s2; }
    __syncthreads();
    if (threadIdx.x == 0) {
        double a_sum = 0, e_sum = 0, vsum = 0;
        #pragma unroll
        for (int w = 0; w < 4; ++w) { a_sum += sh[0][w]; e_sum += sh[1][w]; vsum += sh[2][w]; }
        const double M = (double)M_TOT;
        out[0] = (float)(0.25 * vsum / M - a_sum / M - 0.01 * e_sum / M);
    }
}

// ---------------------------------------------------------------------------
extern "C" void kernel_launch(void* const* d_in, const int* in_sizes, int n_in,
                              void* d_out, int out_size, void* d_ws, size_t ws_size,
                              hipStream_t stream) {
    const float* rewards     = (const float*)d_in[0];   // (T, N)
    const float* masks       = (const float*)d_in[1];   // (T+1, N)
    const float* bad_masks   = (const float*)d_in[2];   // (T+1, N)
    const float* value_preds = (const float*)d_in[3];   // (T+1, N)
    const float* last_value  = (const float*)d_in[4];   // (N,)
    const float* log_prob    = (const float*)d_in[5];   // (T, N)
    const float* prev_lp     = (const float*)d_in[6];   // (T, N)
    const float* new_value   = (const float*)d_in[7];   // (T, N)
    const float* dist_ent    = (const float*)d_in[8];   // (T, N)

    char* ws = (char*)d_ws;
    double* pg  = (double*)(ws + 256);
    double* pl  = (double*)(ws + 32768);
    unsigned short* b16 = (unsigned short*)(ws + 65536);
    float* A = (float*)(ws + 65536 + (size_t)M_TOT * 2);
    float* B = (float*)(ws + 65536 + (size_t)M_TOT * 2 + (size_t)C_CHUNKS * N_DIM * 4);

    k_pc<<<PC_BLOCKS, 256, 0, stream>>>((const float4*)rewards,
                                        (const float4*)masks,
                                        (const float4*)bad_masks,
                                        (const float4*)value_preds,
                                        (const float4*)last_value,
                                        (ushort4*)b16, (float4*)A, (float4*)B);
    k_scan<<<SCAN_BLOCKS, 256, 0, stream>>>((float4*)A, (const float4*)B);
    k_gae<<<PC_BLOCKS, 256, 0, stream>>>((const ushort4*)b16,
                                         (const float4*)A /* g_in */,
                                         (const float4*)value_preds,
                                         (const float4*)new_value, pg);
    k_loss<<<PC_BLOCKS, 256, 0, stream>>>((const ushort4*)b16,
                                          (const float4*)A /* g_in */,
                                          (const float4*)log_prob,
                                          (const float4*)prev_lp,
                                          (const float4*)dist_ent, pg, pl);
    k_final<<<1, 256, 0, stream>>>(pg, pl, (float*)d_out);
}